// Round 8
// baseline (127.528 us; speedup 1.0000x reference)
//
#include <hip/hip_runtime.h>
#include <hip/hip_bf16.h>

// FlashAttentionVarlen, bf16 32x32x16-MFMA flash attention, fp32 in/out.
// B=128 seqs (L in {128,256}), H=16, D=64, packed T=24576.
// Block = (seq b, head h, 128-row q chunk): 256 thr = 4 waves x 32 q rows.
// Swapped QK (mfma32(A=K,B=Q)) -> lane (hi,qj) holds 32 of 64 tile-keys for
// q-row qj in regs; softmax row-reduce and P->PV-A redistribute use
// __shfl_xor(.,32) ONLY (HIP-defined semantics; R6/R7 failed on the
// direction ambiguity of raw v_permlane32_swap_b32 in the P redistribute).
// K split bf16 hi/lo (QK error ~2^-17), V bf16-hi, P split hi/lo.
// LDS double-buffered, one barrier per tile; raw s_barrier + lgkmcnt keeps
// prefetch in flight. XCD pair-swizzle as R5.

using bf16x8 = __attribute__((ext_vector_type(8))) short;
using u16x8  = __attribute__((ext_vector_type(8))) unsigned short;
using u32x4  = __attribute__((ext_vector_type(4))) unsigned;
using f32x16 = __attribute__((ext_vector_type(16))) float;

#define MFMA32(a, b, c) __builtin_amdgcn_mfma_f32_32x32x16_bf16((a), (b), (c), 0, 0, 0)

constexpr int H  = 16;
constexpr int D  = 64;
constexpr int RS = H * D;                              // packed row stride (floats)
constexpr float QSCALE = 0.125f * 1.44269504088896f;   // 1/sqrt(64) * log2(e)
constexpr float THR    = 11.5f;                        // defer-max threshold (log2)

__device__ inline unsigned short bfbits(float x) {
  return __builtin_bit_cast(unsigned short, __float2bfloat16(x));
}
__device__ inline float bff(unsigned short u) {
  unsigned v = ((unsigned)u) << 16;
  return __builtin_bit_cast(float, v);
}
__device__ inline unsigned pack2(float x, float y) {
  return (unsigned)bfbits(x) | ((unsigned)bfbits(y) << 16);
}

__global__ __launch_bounds__(256, 3)
void fa_mfma7_kernel(const float* __restrict__ qg, const float* __restrict__ kg,
                     const float* __restrict__ vg, const int* __restrict__ cu,
                     float* __restrict__ outg) {
  // double-buffered planes: K hi/lo [key][d] (slot ^= key&7), V^T [d][key] (slot ^= d&7)
  __shared__ unsigned short kph[2][64 * 64];
  __shared__ unsigned short kpl[2][64 * 64];
  __shared__ unsigned short vth[2][64 * 64];
  __shared__ float lsc[4 * 32];          // per-wave lane->reg bounce (corr / 1/l)

  // XCD pair swizzle (verified R5): both chunks of one (b,h) same XCD, close in time
  const int bid   = (int)blockIdx.x;
  const int pp    = ((bid >> 4) << 3) + (bid & 7);
  const int chunk = (bid >> 3) & 1;
  const int b = pp >> 4, h = pp & 15;

  const int t0 = cu[b];
  const int L  = cu[b + 1] - t0;
  if (chunk * 128 >= L) return;          // block-uniform early exit
  const int nt = L >> 6;                 // 64-key tiles: 2 or 4

  const int tid = (int)threadIdx.x, lane = tid & 63, w = tid >> 6;
  const int hi = lane >> 5, qj = lane & 31;
  const int qbase = chunk * 128 + w * 32;

  // staging maps (256 threads)
  const int k_key = tid >> 2, kd0 = (tid & 3) * 16;
  const int kidx0 = k_key * 64 + ((((kd0 >> 3) + 0) ^ (k_key & 7)) << 3);
  const int kidx1 = k_key * 64 + ((((kd0 >> 3) + 1) ^ (k_key & 7)) << 3);
  const int v_d = tid & 63, vk0 = (tid >> 6) * 16;
  const int vidx0 = v_d * 64 + ((((vk0 >> 3) + 0) ^ (v_d & 7)) << 3);
  const int vidx1 = v_d * 64 + ((((vk0 >> 3) + 1) ^ (v_d & 7)) << 3);

  const float* kbase = kg + (size_t)t0 * RS + h * D;
  const float* vbase = vg + (size_t)t0 * RS + h * D;

  // ---- Q fragments (B operand): lane holds Q[qj][ks*16 + hi*8 + jj] ----
  bf16x8 qh[4], ql[4];
  {
    const float* qrow = qg + (size_t)(t0 + qbase + qj) * RS + h * D;
#pragma unroll
    for (int ks = 0; ks < 4; ++ks) {
      const int d0 = ks * 16 + hi * 8;
      const float4 f0 = *reinterpret_cast<const float4*>(qrow + d0);
      const float4 f1 = *reinterpret_cast<const float4*>(qrow + d0 + 4);
      const float f[8] = {f0.x, f0.y, f0.z, f0.w, f1.x, f1.y, f1.z, f1.w};
#pragma unroll
      for (int j = 0; j < 8; ++j) {
        const float x = f[j] * QSCALE;
        const unsigned short hs = bfbits(x);
        qh[ks][j] = (short)hs;
        ql[ks][j] = (short)bfbits(x - bff(hs));
      }
    }
  }

  f32x16 acc0, acc1;                     // O rows=q(reg), cols=d (n*32+qj)
#pragma unroll
  for (int r = 0; r < 16; ++r) { acc0[r] = 0.f; acc1[r] = 0.f; }
  float m = -1e30f, lsum = 0.f;

  // ---- staging: reg prefetch -> cvt -> ds_write ----
  float kf[16], vf[16];
  auto load_t = [&](int t) {
    const float* kr = kbase + (size_t)(t * 64 + k_key) * RS + kd0;
#pragma unroll
    for (int i = 0; i < 16; i += 4) {
      const float4 f4 = *reinterpret_cast<const float4*>(kr + i);
      kf[i] = f4.x; kf[i + 1] = f4.y; kf[i + 2] = f4.z; kf[i + 3] = f4.w;
    }
    const float* vp = vbase + (size_t)(t * 64 + vk0) * RS + v_d;
#pragma unroll
    for (int i = 0; i < 16; ++i) vf[i] = vp[(size_t)i * RS];
  };
  auto cvt_write = [&](int buf) {
    u16x8 h0, h1, l0, l1, v0, v1;
#pragma unroll
    for (int i = 0; i < 8; ++i) {
      const unsigned short a = bfbits(kf[i]), c = bfbits(kf[8 + i]);
      h0[i] = a; l0[i] = bfbits(kf[i] - bff(a));
      h1[i] = c; l1[i] = bfbits(kf[8 + i] - bff(c));
      v0[i] = bfbits(vf[i]);
      v1[i] = bfbits(vf[8 + i]);
    }
    *reinterpret_cast<u16x8*>(&kph[buf][kidx0]) = h0;
    *reinterpret_cast<u16x8*>(&kph[buf][kidx1]) = h1;
    *reinterpret_cast<u16x8*>(&kpl[buf][kidx0]) = l0;
    *reinterpret_cast<u16x8*>(&kpl[buf][kidx1]) = l1;
    *reinterpret_cast<u16x8*>(&vth[buf][vidx0]) = v0;
    *reinterpret_cast<u16x8*>(&vth[buf][vidx1]) = v1;
  };

  // ---- P pack: 8 exp'd scores of one C-tile -> A-frags for 16 keys ----
  // Lane (hi,qj): x[i] = P[key (i&3)+8*(i>>2)+4*hi][qj].
  //   a0=(k0,k1) a1=(k2,k3) a2=(k8,k9) a3=(k10,k11)  (+4 if hi)
  // Need words: hi=0 {k0k1,k2k3,k4k5,k6k7}; hi=1 {k8k9,k10k11,k12k13,k14k15}.
  //   w0 = hi ? cross(a2) : a0    w2 = hi ? a2 : cross(a0)
  //   w1 = hi ? cross(a3) : a1    w3 = hi ? a3 : cross(a1)
  // folded to 2 shuffles: t02 = hi?a0:a2 -> cross gives (8,9)/(4,5); t13 likewise.
  const bool hib = (hi != 0);
  auto mix4 = [&](unsigned a0, unsigned a1, unsigned a2, unsigned a3) -> u32x4 {
    const unsigned t02 = hib ? a0 : a2;
    const unsigned t13 = hib ? a1 : a3;
    const unsigned c02 = (unsigned)__shfl_xor((int)t02, 32);
    const unsigned c13 = (unsigned)__shfl_xor((int)t13, 32);
    u32x4 r;
    r[0] = hib ? c02 : a0;
    r[1] = hib ? c13 : a1;
    r[2] = hib ? a2 : c02;
    r[3] = hib ? a3 : c13;
    return r;
  };
  auto build_pa = [&](const float* x, bf16x8& pah, bf16x8& pal) {
    pah = __builtin_bit_cast(bf16x8,
        mix4(pack2(x[0], x[1]), pack2(x[2], x[3]),
             pack2(x[4], x[5]), pack2(x[6], x[7])));
    float y[8];
#pragma unroll
    for (int i = 0; i < 8; ++i) y[i] = x[i] - bff(bfbits(x[i]));
    pal = __builtin_bit_cast(bf16x8,
        mix4(pack2(y[0], y[1]), pack2(y[2], y[3]),
             pack2(y[4], y[5]), pack2(y[6], y[7])));
  };

  // ---- compute one 64-key tile ----
  auto compute = [&](int buf) {
    const unsigned short* KH = kph[buf];
    const unsigned short* KL = kpl[buf];
    const unsigned short* VT = vth[buf];
    // QK^T swapped: sc rows=key (reg-dim), cols=q (lane-dim)
    f32x16 sc0, sc1;
#pragma unroll
    for (int r = 0; r < 16; ++r) { sc0[r] = 0.f; sc1[r] = 0.f; }
    __builtin_amdgcn_s_setprio(1);
#pragma unroll
    for (int kt = 0; kt < 2; ++kt) {
#pragma unroll
      for (int ks = 0; ks < 4; ++ks) {
        const int idx = (kt * 32 + qj) * 64 + (((ks * 2 + hi) ^ (qj & 7)) << 3);
        const bf16x8 khi = *reinterpret_cast<const bf16x8*>(&KH[idx]);
        const bf16x8 klo = *reinterpret_cast<const bf16x8*>(&KL[idx]);
        if (kt == 0) {
          sc0 = MFMA32(khi, qh[ks], sc0);
          sc0 = MFMA32(klo, qh[ks], sc0);
          sc0 = MFMA32(khi, ql[ks], sc0);
        } else {
          sc1 = MFMA32(khi, qh[ks], sc1);
          sc1 = MFMA32(klo, qh[ks], sc1);
          sc1 = MFMA32(khi, ql[ks], sc1);
        }
      }
    }
    __builtin_amdgcn_s_setprio(0);

    // ---- softmax: in-register, q = qj (lane-dim); pair lane <-> lane^32 ----
    float tmax = sc0[0];
#pragma unroll
    for (int r = 1; r < 16; ++r) tmax = fmaxf(tmax, sc0[r]);
#pragma unroll
    for (int r = 0; r < 16; ++r) tmax = fmaxf(tmax, sc1[r]);
    tmax = fmaxf(tmax, __shfl_xor(tmax, 32));
    if (!__all(tmax <= m + THR)) {       // first tile + rare later
      const float newm = fmaxf(m, tmax);
      const float corr = exp2f(m - newm);
      m = newm;
      lsum *= corr;
      if (hi == 0) lsc[w * 32 + qj] = corr;    // lane-dim -> reg-dim bounce
      __builtin_amdgcn_wave_barrier();
#pragma unroll
      for (int r = 0; r < 16; ++r) {
        const float c = lsc[w * 32 + ((r & 3) + 8 * (r >> 2) + 4 * hi)];
        acc0[r] *= c; acc1[r] *= c;
      }
    }
    float ps = 0.f;
#pragma unroll
    for (int r = 0; r < 16; ++r) {
      sc0[r] = exp2f(sc0[r] - m); ps += sc0[r];
    }
#pragma unroll
    for (int r = 0; r < 16; ++r) {
      sc1[r] = exp2f(sc1[r] - m); ps += sc1[r];
    }
    lsum += ps + __shfl_xor(ps, 32);

    // ---- PV: O[q][d] via mfma32(A=P, B=V^T), 4 k-steps of 16 keys ----
#pragma unroll
    for (int ks2 = 0; ks2 < 4; ++ks2) {
      float px[8];
#pragma unroll
      for (int i = 0; i < 8; ++i)
        px[i] = (ks2 & 2) ? sc1[(ks2 & 1) * 8 + i] : sc0[(ks2 & 1) * 8 + i];
      bf16x8 pah, pal;
      build_pa(px, pah, pal);
      __builtin_amdgcn_s_setprio(1);
#pragma unroll
      for (int n = 0; n < 2; ++n) {
        const int idx = (n * 32 + qj) * 64 + (((ks2 * 2 + hi) ^ (qj & 7)) << 3);
        const bf16x8 vh = *reinterpret_cast<const bf16x8*>(&VT[idx]);
        if (n == 0) {
          acc0 = MFMA32(pah, vh, acc0);
          acc0 = MFMA32(pal, vh, acc0);
        } else {
          acc1 = MFMA32(pah, vh, acc1);
          acc1 = MFMA32(pal, vh, acc1);
        }
      }
      __builtin_amdgcn_s_setprio(0);
    }
  };

  // ---- main loop: one barrier per tile, dbuf LDS ----
  load_t(0);
  cvt_write(0);
  if (nt > 1) load_t(1);
  asm volatile("s_waitcnt lgkmcnt(0)" ::: "memory");
  __builtin_amdgcn_s_barrier();
  asm volatile("" ::: "memory");

  for (int t = 0; t < nt; ++t) {
    const int cur = t & 1;
    if (t + 1 < nt) {
      cvt_write(cur ^ 1);
      if (t + 2 < nt) load_t(t + 2);
    }
    compute(cur);
    if (t + 1 < nt) {
      asm volatile("s_waitcnt lgkmcnt(0)" ::: "memory");
      __builtin_amdgcn_s_barrier();
      asm volatile("" ::: "memory");
    }
  }

  // ---- epilogue: 1/l per q (lane-dim) -> reg-dim via LDS, store fp32 ----
  if (hi == 0) lsc[w * 32 + qj] = 1.0f / lsum;
  __builtin_amdgcn_wave_barrier();
#pragma unroll
  for (int r = 0; r < 16; ++r) {
    const int row = (r & 3) + 8 * (r >> 2) + 4 * hi;
    const float li = lsc[w * 32 + row];
    float* op = outg + (size_t)(t0 + qbase + row) * RS + h * D + qj;
    op[0]  = acc0[r] * li;
    op[32] = acc1[r] * li;
  }
}

extern "C" void kernel_launch(void* const* d_in, const int* in_sizes, int n_in,
                              void* d_out, int out_size, void* d_ws, size_t ws_size,
                              hipStream_t stream) {
  (void)in_sizes; (void)n_in; (void)d_ws; (void)ws_size; (void)out_size;
  const float* q  = (const float*)d_in[0];
  const float* k  = (const float*)d_in[1];
  const float* v  = (const float*)d_in[2];
  const int*   cu = (const int*)d_in[3];
  float* out = (float*)d_out;

  fa_mfma7_kernel<<<dim3(4096), dim3(256), 0, stream>>>(q, k, v, cu, out);
}